// Round 13
// baseline (266.806 us; speedup 1.0000x reference)
//
#include <hip/hip_runtime.h>

typedef _Float16 f16_t;
typedef __fp16 fp16x2 __attribute__((ext_vector_type(2)));
typedef _Float16 f16x2 __attribute__((ext_vector_type(2)));
typedef _Float16 f16x4 __attribute__((ext_vector_type(4)));
typedef _Float16 f16x8 __attribute__((ext_vector_type(8)));
typedef float f32x4 __attribute__((ext_vector_type(4)));

#define D_MODEL 1024
#define LSEQ 4096
#define NH 16
#define DH 64
// (1/sqrt(64)) * log2(e), folded into Wq so scores feed v_exp_f32 (base-2) directly
#define QSCALE 0.18033688011112042f

#define GLDS16(g, l)                                                     \
    __builtin_amdgcn_global_load_lds(                                    \
        (const __attribute__((address_space(1))) void*)(g),              \
        (__attribute__((address_space(3))) void*)(l), 16, 0, 0)

#define WAIT_VM(n) asm volatile("s_waitcnt vmcnt(" #n ")" ::: "memory")

// ---------------- fp32 -> fp16 conversion (x + all 4 weights, one launch) ----
// Also re-zeroes the 32 row-group release counters used by attn_wo (block 0).
__global__ __launch_bounds__(256) void cvt_all(const float* __restrict__ x,
                                               const float* __restrict__ w0,
                                               const float* __restrict__ w1,
                                               const float* __restrict__ w2,
                                               const float* __restrict__ w3,
                                               f16_t* __restrict__ xb,
                                               f16_t* __restrict__ wq,
                                               unsigned int* __restrict__ cnt) {
    const int id = blockIdx.x;
    if (id == 0 && threadIdx.x < 32) cnt[threadIdx.x] = 0;
    const float* src;
    f16_t* dst;
    float scale = 1.f;
    int i;
    if (id < 4096) {                       // x part
        src = x; dst = xb;
        i = (id * 256 + threadIdx.x) * 4;
    } else {                               // weight part
        const int r = id - 4096;
        const int q = r >> 10;             // 0..3
        src = (q == 0) ? w0 : (q == 1) ? w1 : (q == 2) ? w2 : w3;
        if (q == 0) scale = QSCALE;
        dst = wq + (size_t)q * (D_MODEL * D_MODEL);
        i = ((r & 1023) * 256 + threadIdx.x) * 4;
    }
    float4 v = *(const float4*)&src[i];
    alignas(8) f16_t o4[4] = {(f16_t)(v.x * scale), (f16_t)(v.y * scale),
                              (f16_t)(v.z * scale), (f16_t)(v.w * scale)};
    *(uint2*)&dst[i] = *(const uint2*)o4;
}

// ---------------- fp16 GEMM: C = A @ B^T, fused V-fragmenting epilogue ------
// QKV: col-groups 0..31 (Q,K heads) stored direct as [grp][row][64];
// col-groups >= 32 (V heads) written as the x32 A-operand fragment image
// (kappa layout) straight from acc via an LDS transpose.
__global__ __launch_bounds__(256, 3) void gemm_f16(const f16_t* __restrict__ A,
                                                   const f16_t* __restrict__ B,
                                                   void* __restrict__ Cout,
                                                   f16_t* __restrict__ v4out,
                                                   int M, int N, int K, int mode) {
    __shared__ alignas(16) f16_t sm[24576];

    const int tid  = threadIdx.x;
    const int wave = tid >> 6;
    const int lane = tid & 63;
    const int quad = lane >> 4;
    const int l16  = lane & 15;
    const int wm = (wave & 1) * 64;
    const int wn = (wave >> 1) * 64;

    const int gx  = gridDim.x;             // M/128 == 32
    const int gy  = gridDim.y;             // N/128
    const int lid = blockIdx.y * gx + blockIdx.x;   // dispatch-linear id
    const int xcd = lid & 7;
    const int sub = lid >> 3;              // [0, gx*gy/8)
    const int bm  = (xcd * (gx >> 3) + sub / gy) * 128;
    const int bn  = (sub % gy) * 128;

    f32x4 acc[4][4] = {};
    const int nk = K / 32;

    auto stage = [&](int kt, int b) {
        const int c0 = wave * 2;
        GLDS16(&A[(size_t)(bm + c0 * 16 + l16) * K + kt * 32 + quad * 8],
               &sm[b * 4096 + c0 * 512]);
        GLDS16(&A[(size_t)(bm + (c0 + 1) * 16 + l16) * K + kt * 32 + quad * 8],
               &sm[b * 4096 + (c0 + 1) * 512]);
        GLDS16(&B[(size_t)(bn + c0 * 16 + l16) * K + kt * 32 + quad * 8],
               &sm[12288 + b * 4096 + c0 * 512]);
        GLDS16(&B[(size_t)(bn + (c0 + 1) * 16 + l16) * K + kt * 32 + quad * 8],
               &sm[12288 + b * 4096 + (c0 + 1) * 512]);
    };

    stage(0, 0);
    stage(1, 1);
    for (int kt = 0; kt < nk; ++kt) {
        const int cb = kt % 3;
        if (kt < nk - 1) WAIT_VM(4);
        else             WAIT_VM(0);
        __syncthreads();
        if (kt + 2 < nk) stage(kt + 2, (kt + 2) % 3);

        f16x8 af[4], bfr[4];
#pragma unroll
        for (int mt = 0; mt < 4; ++mt)
            af[mt] = *(const f16x8*)&sm[cb * 4096 + ((wm >> 4) + mt) * 512 + lane * 8];
#pragma unroll
        for (int nt = 0; nt < 4; ++nt)
            bfr[nt] = *(const f16x8*)&sm[12288 + cb * 4096 + ((wn >> 4) + nt) * 512 + lane * 8];
#pragma unroll
        for (int mt = 0; mt < 4; ++mt)
#pragma unroll
            for (int nt = 0; nt < 4; ++nt)
                acc[mt][nt] = __builtin_amdgcn_mfma_f32_16x16x32_f16(
                    bfr[nt], af[mt], acc[mt][nt], 0, 0, 0);
    }

    const bool isV = (mode == 0) && (bn >= 2 * D_MODEL);
    if (!isV) {
#pragma unroll
        for (int mt = 0; mt < 4; ++mt)
#pragma unroll
            for (int nt = 0; nt < 4; ++nt) {
                int row = bm + wm + mt * 16 + l16;
                int col = bn + wn + nt * 16 + quad * 4;
                if (mode == 0) {
                    f16x4 p = {(f16_t)acc[mt][nt][0], (f16_t)acc[mt][nt][1],
                               (f16_t)acc[mt][nt][2], (f16_t)acc[mt][nt][3]};
                    *(f16x4*)&((f16_t*)Cout)[((size_t)(col >> 6) * M + row) * 64 +
                                             (col & 63)] = p;
                } else {
                    *(f32x4*)&((float*)Cout)[(size_t)row * N + col] = acc[mt][nt];
                }
            }
    } else {
        // ---- fused V fragmenting ----
        __syncthreads();   // everyone done reading As/Bs
#pragma unroll
        for (int mt = 0; mt < 4; ++mt)
#pragma unroll
            for (int nt = 0; nt < 4; ++nt) {
                f16x4 p = {(f16_t)acc[mt][nt][0], (f16_t)acc[mt][nt][1],
                           (f16_t)acc[mt][nt][2], (f16_t)acc[mt][nt][3]};
                *(f16x4*)&sm[(wm + mt * 16 + l16) * 136 + wn + nt * 16 + quad * 4] = p;
            }
        __syncthreads();
        const int hh = wave >> 1, lt = wave & 1;
        const int head = ((bn - 2 * D_MODEL) >> 6) + hh;
        const int ltg  = (bm >> 6) + lt;
        const int g = lane >> 4, l16f = lane & 15;
        f16_t* dst = v4out + (size_t)head * (LSEQ * DH) + (size_t)ltg * 4096;
#pragma unroll
        for (int c8 = 0; c8 < 8; ++c8) {
            const int mtp = c8 >> 2, dt = c8 & 3;
            alignas(16) f16_t buf[8];
#pragma unroll
            for (int j = 0; j < 8; ++j) {
                int key = lt * 64 + mtp * 32 + (j < 4 ? 4 * g + j : 16 + 4 * g + (j - 4));
                buf[j] = sm[key * 136 + hh * 64 + dt * 16 + l16f];
            }
            *(uint4*)&dst[c8 * 512 + lane * 8] = *(const uint4*)buf;
        }
    }
}

// ---------------- attention + Wo, fused producer/consumer -------------------
// Blocks 0..511: R12 attn body (byte-identical math) -> release cnt[rowgroup].
// Blocks 512..767: spin (device-scope atomic poll) until their row-group's 16
// head-blocks released, acquire-fence, then R12 Wo body (128x128, 8 waves).
// Deadlock-free regardless of placement: attn blocks never wait, so queued
// blocks always drain.  rocprof isolated replays: cnt persists >=16 -> no spin.
__global__ __launch_bounds__(512, 4) void attn_wo(
        const f16_t* __restrict__ qh, const f16_t* __restrict__ kh,
        const f16_t* __restrict__ v4, f16_t* __restrict__ ao,
        const f16_t* __restrict__ wo, float* __restrict__ outF,
        unsigned int* __restrict__ cnt) {
    __shared__ alignas(16) f16_t smem[32768];
    __shared__ alignas(16) float lscr[8 * 64];

    const int tid  = threadIdx.x;
    const int wave = tid >> 6;        // 0..7
    const int lane = tid & 63;
    const int quad = lane >> 4;
    const int l16  = lane & 15;

    if (blockIdx.x < 512) {
        // ================= attention (R12 body) =================
        f16_t* KsB = smem;          // [kha][buf][4096]
        f16_t* VsB = smem + 16384;  // [kha][buf][4096]
        const int wq  = wave & 3;   // q sub-panel
        const int kha = wave >> 2;  // key half

        const int id = blockIdx.x;
        const int head = id & 15;   // blocks of a head share an XCD (head%8)
        const int qrow0 = (id >> 4) * 128 + wq * 32;

        const f16_t* Q  = qh + (size_t)head * LSEQ * DH;
        const f16_t* K  = kh + (size_t)head * LSEQ * DH;
        const f16_t* V4 = v4 + (size_t)head * (LSEQ * DH);

        f16x8 qf[2][2];
#pragma unroll
        for (int qt = 0; qt < 2; ++qt)
#pragma unroll
            for (int kc = 0; kc < 2; ++kc)
                qf[qt][kc] = *(const f16x8*)
                    &Q[(size_t)(qrow0 + qt * 16 + l16) * DH + kc * 32 + quad * 8];

        f32x4 o[4][2] = {};
        float lp[2] = {0.f, 0.f};

        auto stage = [&](int kt, int b) {  // 4 GLDS per wave
            f16_t* ks = KsB + (kha * 2 + b) * 4096;
            f16_t* vs = VsB + (kha * 2 + b) * 4096;
            const int ktg = kha * 32 + kt;  // global 64-key tile index
#pragma unroll
            for (int jj = 0; jj < 2; ++jj) {
                const int j = wq * 2 + jj;               // K chunk: mt=wq, kc=jj
                GLDS16(&K[(size_t)(ktg * 64 + wq * 16 + l16) * DH + jj * 32 + quad * 8],
                       &ks[j * 512]);
                GLDS16(&V4[(size_t)ktg * 4096 + wq * 1024 + jj * 512 + lane * 8],
                       &vs[wq * 1024 + jj * 512]);
            }
        };

        const int NT = LSEQ / 2 / 64;  // 32 tiles per half
        stage(0, 0);
        for (int kt = 0; kt < NT; ++kt) {
            const int cb = kt & 1;
            WAIT_VM(0);
            __syncthreads();
            if (kt + 1 < NT) stage(kt + 1, cb ^ 1);

            const f16_t* ks = KsB + (kha * 2 + cb) * 4096;
            const f16_t* vs = VsB + (kha * 2 + cb) * 4096;

            // ---- QK for BOTH 32-key blocks up front (pipe-mix enabler) ----
            f32x4 sA[2][2] = {};
            {
                f16x8 kfA[4];
#pragma unroll
                for (int c = 0; c < 4; ++c)
                    kfA[c] = *(const f16x8*)&ks[c * 512 + lane * 8];
#pragma unroll
                for (int h = 0; h < 2; ++h)
#pragma unroll
                    for (int qt = 0; qt < 2; ++qt) {
                        sA[h][qt] = __builtin_amdgcn_mfma_f32_16x16x32_f16(
                            kfA[h * 2 + 0], qf[qt][0], sA[h][qt], 0, 0, 0);
                        sA[h][qt] = __builtin_amdgcn_mfma_f32_16x16x32_f16(
                            kfA[h * 2 + 1], qf[qt][1], sA[h][qt], 0, 0, 0);
                    }
            }
            f32x4 sB[2][2] = {};
            {
                f16x8 kfB[4];
#pragma unroll
                for (int c = 0; c < 4; ++c)
                    kfB[c] = *(const f16x8*)&ks[(4 + c) * 512 + lane * 8];
#pragma unroll
                for (int h = 0; h < 2; ++h)
#pragma unroll
                    for (int qt = 0; qt < 2; ++qt) {
                        sB[h][qt] = __builtin_amdgcn_mfma_f32_16x16x32_f16(
                            kfB[h * 2 + 0], qf[qt][0], sB[h][qt], 0, 0, 0);
                        sB[h][qt] = __builtin_amdgcn_mfma_f32_16x16x32_f16(
                            kfB[h * 2 + 1], qf[qt][1], sB[h][qt], 0, 0, 0);
                    }
            }

#pragma unroll
            for (int mtp = 0; mtp < 2; ++mtp) {
                f32x4 (*s)[2] = (mtp == 0) ? sA : sB;

                f16x8 vfd[4];
#pragma unroll
                for (int dt = 0; dt < 4; ++dt)
                    vfd[dt] = *(const f16x8*)&vs[(mtp * 4 + dt) * 512 + lane * 8];

#pragma unroll
                for (int qt = 0; qt < 2; ++qt) {
                    float e0 = __builtin_amdgcn_exp2f(s[0][qt][0]);
                    float e1 = __builtin_amdgcn_exp2f(s[0][qt][1]);
                    float e2 = __builtin_amdgcn_exp2f(s[0][qt][2]);
                    float e3 = __builtin_amdgcn_exp2f(s[0][qt][3]);
                    float e4 = __builtin_amdgcn_exp2f(s[1][qt][0]);
                    float e5 = __builtin_amdgcn_exp2f(s[1][qt][1]);
                    float e6 = __builtin_amdgcn_exp2f(s[1][qt][2]);
                    float e7 = __builtin_amdgcn_exp2f(s[1][qt][3]);
                    lp[qt] += ((e0 + e1) + (e2 + e3)) + ((e4 + e5) + (e6 + e7));
                    fp16x2 p01 = __builtin_amdgcn_cvt_pkrtz(e0, e1);
                    fp16x2 p23 = __builtin_amdgcn_cvt_pkrtz(e2, e3);
                    fp16x2 p45 = __builtin_amdgcn_cvt_pkrtz(e4, e5);
                    fp16x2 p67 = __builtin_amdgcn_cvt_pkrtz(e6, e7);
                    f16x8 p = {__builtin_bit_cast(f16x2, p01)[0],
                               __builtin_bit_cast(f16x2, p01)[1],
                               __builtin_bit_cast(f16x2, p23)[0],
                               __builtin_bit_cast(f16x2, p23)[1],
                               __builtin_bit_cast(f16x2, p45)[0],
                               __builtin_bit_cast(f16x2, p45)[1],
                               __builtin_bit_cast(f16x2, p67)[0],
                               __builtin_bit_cast(f16x2, p67)[1]};
#pragma unroll
                    for (int dt = 0; dt < 4; ++dt)
                        o[dt][qt] = __builtin_amdgcn_mfma_f32_16x16x32_f16(
                            vfd[dt], p, o[dt][qt], 0, 0, 0);
                }
            }
        }

        // ---- merge the two key-halves (pure sums) ----
        __syncthreads();
        float* scr = (float*)smem;   // 32 KB used
        if (wave >= 4) {
#pragma unroll
            for (int dt = 0; dt < 4; ++dt)
#pragma unroll
                for (int qt = 0; qt < 2; ++qt)
                    *(f32x4*)&scr[(((wave - 4) * 8 + dt * 2 + qt) * 64 + lane) * 4] =
                        o[dt][qt];
#pragma unroll
            for (int qt = 0; qt < 2; ++qt)
                lscr[((wave - 4) * 2 + qt) * 64 + lane] = lp[qt];
        }
        __syncthreads();
        if (wave < 4) {
#pragma unroll
            for (int dt = 0; dt < 4; ++dt)
#pragma unroll
                for (int qt = 0; qt < 2; ++qt)
                    o[dt][qt] += *(const f32x4*)
                        &scr[((wave * 8 + dt * 2 + qt) * 64 + lane) * 4];
#pragma unroll
            for (int qt = 0; qt < 2; ++qt) {
                float t = lp[qt] + lscr[(wave * 2 + qt) * 64 + lane];
                t += __shfl_xor(t, 16, 64);
                t += __shfl_xor(t, 32, 64);
                lp[qt] = 1.f / t;
            }
#pragma unroll
            for (int dt = 0; dt < 4; ++dt)
#pragma unroll
                for (int qt = 0; qt < 2; ++qt) {
                    f16x4 ov = {(f16_t)(o[dt][qt][0] * lp[qt]),
                                (f16_t)(o[dt][qt][1] * lp[qt]),
                                (f16_t)(o[dt][qt][2] * lp[qt]),
                                (f16_t)(o[dt][qt][3] * lp[qt])};
                    int qrow = qrow0 + qt * 16 + l16;
                    *(f16x4*)&ao[(size_t)qrow * D_MODEL + head * 64 + dt * 16 +
                                 quad * 4] = ov;
                }
        }

        // ---- release: row-group (id>>4) of ao is complete ----
        __syncthreads();                 // all waves' ao stores issued
        if (tid == 0) {
            __threadfence();             // device-scope: writeback before signal
            atomicAdd(&cnt[id >> 4], 1u);
        }
    } else {
        // ================= Wo GEMM (R12 body), gated on producer ============
        const int wid = blockIdx.x - 512;        // 0..255
        const int rg  = wid >> 3;                // row-group 0..31 (= bm/128)
        const int bm  = rg * 128;
        const int bn  = (wid & 7) * 128;

        if (tid == 0) {
            while (atomicAdd(&cnt[rg], 0u) < 16u)
                __builtin_amdgcn_s_sleep(16);
            __threadfence();             // device-scope acquire before ao reads
        }
        __syncthreads();

        f16_t* sm = smem;                // 48KB of the 64KB union
        const int wm = (wave & 1) * 64;  // 2 m-positions x 64 rows
        const int wn = (wave >> 1) * 32; // 4 n-positions x 32 cols
        const int K = D_MODEL;

        f32x4 acc[4][2] = {};
        const int nk = K / 32;   // 32

        auto stageW = [&](int kt, int b) {  // wave w: A chunk w + B chunk w
            f16_t* base = sm + b * 8192;
            GLDS16(&ao[(size_t)(bm + wave * 16 + l16) * K + kt * 32 + quad * 8],
                   &base[wave * 512]);
            GLDS16(&wo[(size_t)(bn + wave * 16 + l16) * K + kt * 32 + quad * 8],
                   &base[4096 + wave * 512]);
        };

        stageW(0, 0);
        stageW(1, 1);
        for (int kt = 0; kt < nk; ++kt) {
            const int cb = kt % 3;
            if (kt < nk - 1) WAIT_VM(2);
            else             WAIT_VM(0);
            __syncthreads();
            if (kt + 2 < nk) stageW(kt + 2, (kt + 2) % 3);

            f16x8 af[4], bfr[2];
#pragma unroll
            for (int mt = 0; mt < 4; ++mt)
                af[mt] = *(const f16x8*)&sm[cb * 8192 + ((wm >> 4) + mt) * 512 + lane * 8];
#pragma unroll
            for (int nt = 0; nt < 2; ++nt)
                bfr[nt] = *(const f16x8*)&sm[cb * 8192 + 4096 + ((wn >> 4) + nt) * 512 + lane * 8];
#pragma unroll
            for (int mt = 0; mt < 4; ++mt)
#pragma unroll
                for (int nt = 0; nt < 2; ++nt)
                    acc[mt][nt] = __builtin_amdgcn_mfma_f32_16x16x32_f16(
                        bfr[nt], af[mt], acc[mt][nt], 0, 0, 0);
        }

#pragma unroll
        for (int mt = 0; mt < 4; ++mt)
#pragma unroll
            for (int nt = 0; nt < 2; ++nt) {
                int row = bm + wm + mt * 16 + l16;
                int col = bn + wn + nt * 16 + quad * 4;
                *(f32x4*)&outF[(size_t)row * D_MODEL + col] = acc[mt][nt];
            }
    }
}

extern "C" void kernel_launch(void* const* d_in, const int* in_sizes, int n_in,
                              void* d_out, int out_size, void* d_ws, size_t ws_size,
                              hipStream_t stream) {
    const float* x  = (const float*)d_in[0];
    const float* Wq = (const float*)d_in[1];
    const float* Wk = (const float*)d_in[2];
    const float* Wv = (const float*)d_in[3];
    const float* Wo = (const float*)d_in[4];

    f16_t* xb = (f16_t*)d_ws;                        // [4096][1024]
    f16_t* wq = xb + (size_t)LSEQ * D_MODEL;         // [3072][1024] qkv concat
    f16_t* wo = wq + (size_t)3 * D_MODEL * D_MODEL;  // [1024][1024]
    f16_t* qh = wo + (size_t)D_MODEL * D_MODEL;      // [16][4096][64]
    f16_t* kh = qh + (size_t)LSEQ * D_MODEL;
    f16_t* vh = kh + (size_t)LSEQ * D_MODEL;         // (unused)
    f16_t* v4 = vh + (size_t)LSEQ * D_MODEL;         // fragmented V
    f16_t* ao = v4 + (size_t)LSEQ * D_MODEL;         // [4096][1024]
    unsigned int* cnt = (unsigned int*)(ao + (size_t)LSEQ * D_MODEL);  // 32 ctrs

    // x (4096 blocks) + 4 weights (4*1024 blocks) in one launch; zeroes cnt
    cvt_all<<<4096 + 4 * 1024, 256, 0, stream>>>(x, Wq, Wk, Wv, Wo, xb, wq, cnt);

    // QKV GEMM with fused V-fragmenting epilogue
    gemm_f16<<<dim3(LSEQ / 128, 3 * D_MODEL / 128), 256, 0, stream>>>(
        xb, wq, qh, v4, LSEQ, 3 * D_MODEL, D_MODEL, 0);

    // fused attention (blocks 0..511) + Wo GEMM (blocks 512..767)
    attn_wo<<<dim3(512 + 256), 512, 0, stream>>>(
        qh, kh, v4, ao, wo, (float*)d_out, cnt);
}

// Round 14
// 228.591 us; speedup vs baseline: 1.1672x; 1.1672x over previous
//
#include <hip/hip_runtime.h>

typedef _Float16 f16_t;
typedef __fp16 fp16x2 __attribute__((ext_vector_type(2)));
typedef _Float16 f16x2 __attribute__((ext_vector_type(2)));
typedef _Float16 f16x4 __attribute__((ext_vector_type(4)));
typedef _Float16 f16x8 __attribute__((ext_vector_type(8)));
typedef float f32x4 __attribute__((ext_vector_type(4)));

#define D_MODEL 1024
#define LSEQ 4096
#define NH 16
#define DH 64
// (1/sqrt(64)) * log2(e), folded into Wq so scores feed v_exp_f32 (base-2) directly
#define QSCALE 0.18033688011112042f

#define GLDS16(g, l)                                                     \
    __builtin_amdgcn_global_load_lds(                                    \
        (const __attribute__((address_space(1))) void*)(g),              \
        (__attribute__((address_space(3))) void*)(l), 16, 0, 0)

#define WAIT_VM(n) asm volatile("s_waitcnt vmcnt(" #n ")" ::: "memory")

// ---------------- fp32 -> fp16 conversion (x + all 4 weights) ----------------
// 2048 blocks, x4 grid-stride (guideline 11: cap blocks, stride the rest).
__global__ __launch_bounds__(256) void cvt_all(const float* __restrict__ x,
                                               const float* __restrict__ w0,
                                               const float* __restrict__ w1,
                                               const float* __restrict__ w2,
                                               const float* __restrict__ w3,
                                               f16_t* __restrict__ xb,
                                               f16_t* __restrict__ wq) {
    const int NX = (LSEQ * D_MODEL) / 4;       // 1048576 x-quads
    const int NW = (D_MODEL * D_MODEL) / 4;    // 262144 quads per weight
    for (int i = blockIdx.x * 256 + threadIdx.x; i < NX + 4 * NW;
         i += 2048 * 256) {
        const float* src; f16_t* dst; float scale = 1.f; int e;
        if (i < NX) { src = x; dst = xb; e = i; }
        else {
            int j = i - NX;
            int q = j >> 18;                   // NW == 2^18
            e = j & (NW - 1);
            src = (q == 0) ? w0 : (q == 1) ? w1 : (q == 2) ? w2 : w3;
            if (q == 0) scale = QSCALE;
            dst = wq + (size_t)q * (D_MODEL * D_MODEL);
        }
        float4 v = *(const float4*)&src[(size_t)e * 4];
        alignas(8) f16_t o4[4] = {(f16_t)(v.x * scale), (f16_t)(v.y * scale),
                                  (f16_t)(v.z * scale), (f16_t)(v.w * scale)};
        *(uint2*)&dst[(size_t)e * 4] = *(const uint2*)o4;
    }
}

// ---------------- fp16 GEMM: C = A @ B^T, fused V-fragmenting epilogue ------
// QKV: col-groups 0..31 (Q,K heads) stored direct as [grp][row][64];
// col-groups >= 32 (V heads) written as the x32 A-operand fragment image
// (kappa layout) straight from acc via an LDS transpose.
__global__ __launch_bounds__(256, 3) void gemm_f16(const f16_t* __restrict__ A,
                                                   const f16_t* __restrict__ B,
                                                   void* __restrict__ Cout,
                                                   f16_t* __restrict__ v4out,
                                                   int M, int N, int K, int mode) {
    __shared__ alignas(16) f16_t sm[24576];

    const int tid  = threadIdx.x;
    const int wave = tid >> 6;
    const int lane = tid & 63;
    const int quad = lane >> 4;
    const int l16  = lane & 15;
    const int wm = (wave & 1) * 64;
    const int wn = (wave >> 1) * 64;

    const int gx  = gridDim.x;             // M/128 == 32
    const int gy  = gridDim.y;             // N/128
    const int lid = blockIdx.y * gx + blockIdx.x;   // dispatch-linear id
    const int xcd = lid & 7;
    const int sub = lid >> 3;              // [0, gx*gy/8)
    const int bm  = (xcd * (gx >> 3) + sub / gy) * 128;
    const int bn  = (sub % gy) * 128;

    f32x4 acc[4][4] = {};
    const int nk = K / 32;

    auto stage = [&](int kt, int b) {
        const int c0 = wave * 2;
        GLDS16(&A[(size_t)(bm + c0 * 16 + l16) * K + kt * 32 + quad * 8],
               &sm[b * 4096 + c0 * 512]);
        GLDS16(&A[(size_t)(bm + (c0 + 1) * 16 + l16) * K + kt * 32 + quad * 8],
               &sm[b * 4096 + (c0 + 1) * 512]);
        GLDS16(&B[(size_t)(bn + c0 * 16 + l16) * K + kt * 32 + quad * 8],
               &sm[12288 + b * 4096 + c0 * 512]);
        GLDS16(&B[(size_t)(bn + (c0 + 1) * 16 + l16) * K + kt * 32 + quad * 8],
               &sm[12288 + b * 4096 + (c0 + 1) * 512]);
    };

    stage(0, 0);
    stage(1, 1);
    for (int kt = 0; kt < nk; ++kt) {
        const int cb = kt % 3;
        if (kt < nk - 1) WAIT_VM(4);
        else             WAIT_VM(0);
        __syncthreads();
        if (kt + 2 < nk) stage(kt + 2, (kt + 2) % 3);

        f16x8 af[4], bfr[4];
#pragma unroll
        for (int mt = 0; mt < 4; ++mt)
            af[mt] = *(const f16x8*)&sm[cb * 4096 + ((wm >> 4) + mt) * 512 + lane * 8];
#pragma unroll
        for (int nt = 0; nt < 4; ++nt)
            bfr[nt] = *(const f16x8*)&sm[12288 + cb * 4096 + ((wn >> 4) + nt) * 512 + lane * 8];
#pragma unroll
        for (int mt = 0; mt < 4; ++mt)
#pragma unroll
            for (int nt = 0; nt < 4; ++nt)
                acc[mt][nt] = __builtin_amdgcn_mfma_f32_16x16x32_f16(
                    bfr[nt], af[mt], acc[mt][nt], 0, 0, 0);
    }

    const bool isV = (mode == 0) && (bn >= 2 * D_MODEL);
    if (!isV) {
#pragma unroll
        for (int mt = 0; mt < 4; ++mt)
#pragma unroll
            for (int nt = 0; nt < 4; ++nt) {
                int row = bm + wm + mt * 16 + l16;
                int col = bn + wn + nt * 16 + quad * 4;
                if (mode == 0) {
                    f16x4 p = {(f16_t)acc[mt][nt][0], (f16_t)acc[mt][nt][1],
                               (f16_t)acc[mt][nt][2], (f16_t)acc[mt][nt][3]};
                    *(f16x4*)&((f16_t*)Cout)[((size_t)(col >> 6) * M + row) * 64 +
                                             (col & 63)] = p;
                } else {
                    *(f32x4*)&((float*)Cout)[(size_t)row * N + col] = acc[mt][nt];
                }
            }
    } else {
        // ---- fused V fragmenting ----
        __syncthreads();   // everyone done reading As/Bs
#pragma unroll
        for (int mt = 0; mt < 4; ++mt)
#pragma unroll
            for (int nt = 0; nt < 4; ++nt) {
                f16x4 p = {(f16_t)acc[mt][nt][0], (f16_t)acc[mt][nt][1],
                           (f16_t)acc[mt][nt][2], (f16_t)acc[mt][nt][3]};
                *(f16x4*)&sm[(wm + mt * 16 + l16) * 136 + wn + nt * 16 + quad * 4] = p;
            }
        __syncthreads();
        const int hh = wave >> 1, lt = wave & 1;
        const int head = ((bn - 2 * D_MODEL) >> 6) + hh;
        const int ltg  = (bm >> 6) + lt;
        const int g = lane >> 4, l16f = lane & 15;
        f16_t* dst = v4out + (size_t)head * (LSEQ * DH) + (size_t)ltg * 4096;
#pragma unroll
        for (int c8 = 0; c8 < 8; ++c8) {
            const int mtp = c8 >> 2, dt = c8 & 3;
            alignas(16) f16_t buf[8];
#pragma unroll
            for (int j = 0; j < 8; ++j) {
                int key = lt * 64 + mtp * 32 + (j < 4 ? 4 * g + j : 16 + 4 * g + (j - 4));
                buf[j] = sm[key * 136 + hh * 64 + dt * 16 + l16f];
            }
            *(uint4*)&dst[c8 * 512 + lane * 8] = *(const uint4*)buf;
        }
    }
}

// ---------------- Wo GEMM: out(f32) = ao @ wo^T ----------------
// 128x128 block tile (256 blocks, grid 32x8) with 512 threads / 8 waves:
// wave tile 64x32 -> acc[4][2], 8 MFMA/wave/K-step, 2 waves/SIMD.
// 3-deep ring, counted WAIT_VM(2).
__global__ __launch_bounds__(512, 2) void gemm_wo(const f16_t* __restrict__ A,
                                                  const f16_t* __restrict__ B,
                                                  float* __restrict__ outF) {
    __shared__ alignas(16) f16_t sm[24576];   // 3 x (A 4096 + B 4096) f16

    const int tid  = threadIdx.x;
    const int wave = tid >> 6;        // 0..7
    const int lane = tid & 63;
    const int quad = lane >> 4;
    const int l16  = lane & 15;
    const int wm = (wave & 1) * 64;   // 2 m-positions x 64 rows
    const int wn = (wave >> 1) * 32;  // 4 n-positions x 32 cols
    const int bm = blockIdx.x * 128;
    const int bn = blockIdx.y * 128;
    const int K = D_MODEL;

    f32x4 acc[4][2] = {};
    const int nk = K / 32;   // 32

    auto stage = [&](int kt, int b) {  // wave w: A chunk w + B chunk w
        f16_t* base = sm + b * 8192;
        GLDS16(&A[(size_t)(bm + wave * 16 + l16) * K + kt * 32 + quad * 8],
               &base[wave * 512]);
        GLDS16(&B[(size_t)(bn + wave * 16 + l16) * K + kt * 32 + quad * 8],
               &base[4096 + wave * 512]);
    };

    stage(0, 0);
    stage(1, 1);
    for (int kt = 0; kt < nk; ++kt) {
        const int cb = kt % 3;
        if (kt < nk - 1) WAIT_VM(2);
        else             WAIT_VM(0);
        __syncthreads();
        if (kt + 2 < nk) stage(kt + 2, (kt + 2) % 3);

        f16x8 af[4], bfr[2];
#pragma unroll
        for (int mt = 0; mt < 4; ++mt)
            af[mt] = *(const f16x8*)&sm[cb * 8192 + ((wm >> 4) + mt) * 512 + lane * 8];
#pragma unroll
        for (int nt = 0; nt < 2; ++nt)
            bfr[nt] = *(const f16x8*)&sm[cb * 8192 + 4096 + ((wn >> 4) + nt) * 512 + lane * 8];
#pragma unroll
        for (int mt = 0; mt < 4; ++mt)
#pragma unroll
            for (int nt = 0; nt < 2; ++nt)
                acc[mt][nt] = __builtin_amdgcn_mfma_f32_16x16x32_f16(
                    bfr[nt], af[mt], acc[mt][nt], 0, 0, 0);
    }

#pragma unroll
    for (int mt = 0; mt < 4; ++mt)
#pragma unroll
        for (int nt = 0; nt < 2; ++nt) {
            int row = bm + wm + mt * 16 + l16;
            int col = bn + wn + nt * 16 + quad * 4;
            *(f32x4*)&outF[(size_t)row * D_MODEL + col] = acc[mt][nt];
        }
}

// ---------------- attention (R9/R12 body, best measured 80.6us) -------------
__global__ __launch_bounds__(512, 4) void attn_kernel(const f16_t* __restrict__ qh,
                                                      const f16_t* __restrict__ kh,
                                                      const f16_t* __restrict__ v4,
                                                      f16_t* __restrict__ ao) {
    // smem: Ks = [0,16K) f16, Vs = [16K,32K) f16; merge reuses as f32 scratch
    __shared__ alignas(16) f16_t smem[32768];
    __shared__ alignas(16) float lscr[8 * 64];
    f16_t* KsB = smem;          // [kha][buf][4096]
    f16_t* VsB = smem + 16384;  // [kha][buf][4096]

    const int tid  = threadIdx.x;
    const int wave = tid >> 6;        // 0..7
    const int lane = tid & 63;
    const int quad = lane >> 4;
    const int l16  = lane & 15;
    const int wq   = wave & 3;        // q sub-panel
    const int kha  = wave >> 2;       // key half

    const int id = blockIdx.x;
    const int head = id & 15;         // blocks of a head share an XCD (head%8)
    const int qrow0 = (id >> 4) * 128 + wq * 32;

    const f16_t* Q  = qh + (size_t)head * LSEQ * DH;
    const f16_t* K  = kh + (size_t)head * LSEQ * DH;
    const f16_t* V4 = v4 + (size_t)head * (LSEQ * DH);

    f16x8 qf[2][2];
#pragma unroll
    for (int qt = 0; qt < 2; ++qt)
#pragma unroll
        for (int kc = 0; kc < 2; ++kc)
            qf[qt][kc] = *(const f16x8*)
                &Q[(size_t)(qrow0 + qt * 16 + l16) * DH + kc * 32 + quad * 8];

    f32x4 o[4][2] = {};
    float lp[2] = {0.f, 0.f};

    auto stage = [&](int kt, int b) {  // 4 GLDS per wave
        f16_t* ks = KsB + (kha * 2 + b) * 4096;
        f16_t* vs = VsB + (kha * 2 + b) * 4096;
        const int ktg = kha * 32 + kt;  // global 64-key tile index
#pragma unroll
        for (int jj = 0; jj < 2; ++jj) {
            const int j = wq * 2 + jj;               // K chunk: mt=wq, kc=jj
            GLDS16(&K[(size_t)(ktg * 64 + wq * 16 + l16) * DH + jj * 32 + quad * 8],
                   &ks[j * 512]);
            // V: pure memcpy of the pre-fragmented image
            GLDS16(&V4[(size_t)ktg * 4096 + wq * 1024 + jj * 512 + lane * 8],
                   &vs[wq * 1024 + jj * 512]);
        }
    };

    const int NT = LSEQ / 2 / 64;  // 32 tiles per half
    stage(0, 0);
    for (int kt = 0; kt < NT; ++kt) {
        const int cb = kt & 1;
        WAIT_VM(0);
        __syncthreads();
        if (kt + 1 < NT) stage(kt + 1, cb ^ 1);

        const f16_t* ks = KsB + (kha * 2 + cb) * 4096;
        const f16_t* vs = VsB + (kha * 2 + cb) * 4096;

        // ---- QK for BOTH 32-key blocks up front (pipe-mix enabler) ----
        f32x4 sA[2][2] = {};   // mtp0: [h][qt]
        {
            f16x8 kfA[4];
#pragma unroll
            for (int c = 0; c < 4; ++c)
                kfA[c] = *(const f16x8*)&ks[c * 512 + lane * 8];
#pragma unroll
            for (int h = 0; h < 2; ++h)
#pragma unroll
                for (int qt = 0; qt < 2; ++qt) {
                    sA[h][qt] = __builtin_amdgcn_mfma_f32_16x16x32_f16(
                        kfA[h * 2 + 0], qf[qt][0], sA[h][qt], 0, 0, 0);
                    sA[h][qt] = __builtin_amdgcn_mfma_f32_16x16x32_f16(
                        kfA[h * 2 + 1], qf[qt][1], sA[h][qt], 0, 0, 0);
                }
        }
        f32x4 sB[2][2] = {};   // mtp1: [h][qt]
        {
            f16x8 kfB[4];
#pragma unroll
            for (int c = 0; c < 4; ++c)
                kfB[c] = *(const f16x8*)&ks[(4 + c) * 512 + lane * 8];
#pragma unroll
            for (int h = 0; h < 2; ++h)
#pragma unroll
                for (int qt = 0; qt < 2; ++qt) {
                    sB[h][qt] = __builtin_amdgcn_mfma_f32_16x16x32_f16(
                        kfB[h * 2 + 0], qf[qt][0], sB[h][qt], 0, 0, 0);
                    sB[h][qt] = __builtin_amdgcn_mfma_f32_16x16x32_f16(
                        kfB[h * 2 + 1], qf[qt][1], sB[h][qt], 0, 0, 0);
                }
        }

        // ---- softmax(mtp0) [VALU] overlaps QK-B drain; then PV-A [MFMA]
        //      overlaps softmax(mtp1); then PV-B ----
#pragma unroll
        for (int mtp = 0; mtp < 2; ++mtp) {
            f32x4 (*s)[2] = (mtp == 0) ? sA : sB;

            f16x8 vfd[4];
#pragma unroll
            for (int dt = 0; dt < 4; ++dt)
                vfd[dt] = *(const f16x8*)&vs[(mtp * 4 + dt) * 512 + lane * 8];

#pragma unroll
            for (int qt = 0; qt < 2; ++qt) {
                float e0 = __builtin_amdgcn_exp2f(s[0][qt][0]);
                float e1 = __builtin_amdgcn_exp2f(s[0][qt][1]);
                float e2 = __builtin_amdgcn_exp2f(s[0][qt][2]);
                float e3 = __builtin_amdgcn_exp2f(s[0][qt][3]);
                float e4 = __builtin_amdgcn_exp2f(s[1][qt][0]);
                float e5 = __builtin_amdgcn_exp2f(s[1][qt][1]);
                float e6 = __builtin_amdgcn_exp2f(s[1][qt][2]);
                float e7 = __builtin_amdgcn_exp2f(s[1][qt][3]);
                lp[qt] += ((e0 + e1) + (e2 + e3)) + ((e4 + e5) + (e6 + e7));
                fp16x2 p01 = __builtin_amdgcn_cvt_pkrtz(e0, e1);
                fp16x2 p23 = __builtin_amdgcn_cvt_pkrtz(e2, e3);
                fp16x2 p45 = __builtin_amdgcn_cvt_pkrtz(e4, e5);
                fp16x2 p67 = __builtin_amdgcn_cvt_pkrtz(e6, e7);
                f16x8 p = {__builtin_bit_cast(f16x2, p01)[0],
                           __builtin_bit_cast(f16x2, p01)[1],
                           __builtin_bit_cast(f16x2, p23)[0],
                           __builtin_bit_cast(f16x2, p23)[1],
                           __builtin_bit_cast(f16x2, p45)[0],
                           __builtin_bit_cast(f16x2, p45)[1],
                           __builtin_bit_cast(f16x2, p67)[0],
                           __builtin_bit_cast(f16x2, p67)[1]};
                // O^T += V^T . P^T : full-rate x32 MFMA, B=p straight from regs
#pragma unroll
                for (int dt = 0; dt < 4; ++dt)
                    o[dt][qt] = __builtin_amdgcn_mfma_f32_16x16x32_f16(
                        vfd[dt], p, o[dt][qt], 0, 0, 0);
            }
        }
    }

    // ---- merge the two key-halves (pure sums) ----
    __syncthreads();
    float* scr = (float*)smem;   // 32 KB used
    if (wave >= 4) {
#pragma unroll
        for (int dt = 0; dt < 4; ++dt)
#pragma unroll
            for (int qt = 0; qt < 2; ++qt)
                *(f32x4*)&scr[(((wave - 4) * 8 + dt * 2 + qt) * 64 + lane) * 4] =
                    o[dt][qt];
#pragma unroll
        for (int qt = 0; qt < 2; ++qt)
            lscr[((wave - 4) * 2 + qt) * 64 + lane] = lp[qt];
    }
    __syncthreads();
    if (wave < 4) {
#pragma unroll
        for (int dt = 0; dt < 4; ++dt)
#pragma unroll
            for (int qt = 0; qt < 2; ++qt)
                o[dt][qt] += *(const f32x4*)
                    &scr[((wave * 8 + dt * 2 + qt) * 64 + lane) * 4];
#pragma unroll
        for (int qt = 0; qt < 2; ++qt) {
            float t = lp[qt] + lscr[(wave * 2 + qt) * 64 + lane];
            t += __shfl_xor(t, 16, 64);
            t += __shfl_xor(t, 32, 64);
            lp[qt] = 1.f / t;
        }
#pragma unroll
        for (int dt = 0; dt < 4; ++dt)
#pragma unroll
            for (int qt = 0; qt < 2; ++qt) {
                f16x4 ov = {(f16_t)(o[dt][qt][0] * lp[qt]),
                            (f16_t)(o[dt][qt][1] * lp[qt]),
                            (f16_t)(o[dt][qt][2] * lp[qt]),
                            (f16_t)(o[dt][qt][3] * lp[qt])};
                int qrow = qrow0 + qt * 16 + l16;
                *(f16x4*)&ao[(size_t)qrow * D_MODEL + head * 64 + dt * 16 +
                             quad * 4] = ov;
            }
    }
}

extern "C" void kernel_launch(void* const* d_in, const int* in_sizes, int n_in,
                              void* d_out, int out_size, void* d_ws, size_t ws_size,
                              hipStream_t stream) {
    const float* x  = (const float*)d_in[0];
    const float* Wq = (const float*)d_in[1];
    const float* Wk = (const float*)d_in[2];
    const float* Wv = (const float*)d_in[3];
    const float* Wo = (const float*)d_in[4];

    f16_t* xb = (f16_t*)d_ws;                        // [4096][1024]
    f16_t* wq = xb + (size_t)LSEQ * D_MODEL;         // [3072][1024] qkv concat
    f16_t* wo = wq + (size_t)3 * D_MODEL * D_MODEL;  // [1024][1024]
    f16_t* qh = wo + (size_t)D_MODEL * D_MODEL;      // [16][4096][64]
    f16_t* kh = qh + (size_t)LSEQ * D_MODEL;
    f16_t* vh = kh + (size_t)LSEQ * D_MODEL;         // (unused)
    f16_t* v4 = vh + (size_t)LSEQ * D_MODEL;         // fragmented V
    f16_t* ao = v4 + (size_t)LSEQ * D_MODEL;         // [4096][1024]

    // x + 4 weights, 2048 blocks x4 grid-stride
    cvt_all<<<2048, 256, 0, stream>>>(x, Wq, Wk, Wv, Wo, xb, wq);

    // QKV GEMM with fused V-fragmenting epilogue
    gemm_f16<<<dim3(LSEQ / 128, 3 * D_MODEL / 128), 256, 0, stream>>>(
        xb, wq, qh, v4, LSEQ, 3 * D_MODEL, D_MODEL, 0);

    attn_kernel<<<dim3((LSEQ / 128) * NH), 512, 0, stream>>>(qh, kh, v4, ao);

    // Wo GEMM: 128x128 tile, 512 threads / 8 waves (2 waves/SIMD + 8 MFMA/step)
    gemm_wo<<<dim3(LSEQ / 128, D_MODEL / 128), 512, 0, stream>>>(
        ao, wo, (float*)d_out);
}